// Round 3
// baseline (230.022 us; speedup 1.0000x reference)
//
#include <hip/hip_runtime.h>
#include <hip/hip_bf16.h>

// GlobalAttn: x = lrelu(concat(q,k) @ w1^T + b1); attn[e,h] = x[e,h,:]·w2[h,:];
// out = segment_softmax(attn, index). E=320000, D=256, K=512, H=4, N=10000.
//
// GEMM: m97-structure, tile 128M x 256N (full N), BK=32, 16 K-steps, 8 waves
// as 2M x 4N (per-wave 64x64 -> 4+4 b128 reads per 16 MFMA = 512 B/MFMA).
// A: fp32 global -> reg -> cvt -> swizzled ds_write (bf16). B: w1 pre-cvt to
// bf16, staged via global_load_lds (linear dest + pre-swizzled source).
// Epilogue fuses bias+lrelu+w2-dot+exp+atomicAdd(segsum) (softmax without
// max-shift: |attn| <= ~5 statistically, exp safe in fp32, shift-invariant).

typedef __attribute__((ext_vector_type(8))) short bf16x8;
typedef __attribute__((ext_vector_type(4))) float f32x4;
typedef __attribute__((ext_vector_type(4))) short s16x4;

#define NNODES 10000

__device__ __forceinline__ short f2bf(float f) {
    __hip_bfloat16 h = __float2bfloat16(f);   // RNE
    return *reinterpret_cast<short*>(&h);
}

__device__ __forceinline__ void gload_lds16(const void* g, void* l) {
    __builtin_amdgcn_global_load_lds(
        (const __attribute__((address_space(1))) unsigned int*)g,
        (__attribute__((address_space(3))) unsigned int*)l, 16, 0, 0);
}

// ---- w1 fp32 [256][512] -> bf16 (once per call, ~3us) ----
__global__ void w1_cvt(const float* __restrict__ w1, short* __restrict__ w1b) {
    int i = (blockIdx.x * 256 + threadIdx.x) * 4;   // 128 blocks x 256 thr x 4
    float4 v = *(const float4*)(w1 + i);
    s16x4 o; o[0] = f2bf(v.x); o[1] = f2bf(v.y); o[2] = f2bf(v.z); o[3] = f2bf(v.w);
    *(s16x4*)(w1b + i) = o;
}

__global__ void seg_init(float* __restrict__ segsum, int n) {
    int i = blockIdx.x * blockDim.x + threadIdx.x;
    if (i < n) segsum[i] = 0.f;
}

// ---------------- main fused GEMM + epilogue ----------------
__global__ __launch_bounds__(512, 4) void attn_gemm(
    const float* __restrict__ q, const float* __restrict__ kk_,
    const short* __restrict__ w1b, const float* __restrict__ b1,
    const float* __restrict__ w2, const int* __restrict__ index,
    float* __restrict__ attn, float* __restrict__ segsum)
{
    __shared__ short lds_a[2][128 * 32];   // bf16, 8 KB per buf
    __shared__ short lds_b[2][256 * 32];   // bf16, 16 KB per buf  (48 KB total)

    const int tid  = threadIdx.x;
    const int lane = tid & 63;
    const int w    = tid >> 6;        // wave 0..7
    const int wm   = w >> 2;          // 0..1 (M, 64 rows each)
    const int wn   = w & 3;           // 0..3 (N, 64 cols each == one head)
    const int l15  = lane & 15;
    const int lhi  = lane >> 4;
    const int row0 = blockIdx.x * 128;   // 320000/128 = 2500 blocks

    // ---- B staging geometry (global_load_lds, linear dest, pre-swz source) ----
    // linear dest slot i: byte (i*8+w)*1024 + lane*16 -> row d=i*128+w*16+(lane>>2),
    // chunk (lane&3); source chunk = (lane&3) ^ ((d>>1)&3) = (lane&3)^((lane>>3)&3)
    const int b_d    = w * 16 + (lane >> 2);
    const int b_csrc = (lane & 3) ^ ((lane >> 3) & 3);
    const size_t b_off0 = (size_t)b_d * 512 + b_csrc * 8;
    const size_t b_off1 = (size_t)(128 + b_d) * 512 + b_csrc * 8;
    const int b_dst0 = w * 1024 + lane * 16;          // bytes
    const int b_dst1 = (8 + w) * 1024 + lane * 16;

    // ---- A staging geometry (reg -> cvt -> swizzled ds_write) ----
    // thread t stages row a_r = t>>2 (0..127), k-chunk a_c = t&3 (8 floats)
    const int a_r = tid >> 2;
    const int a_c = tid & 3;
    const size_t a_goff = (size_t)(row0 + a_r) * 256 + a_c * 8;
    const int a_ldst = a_r * 32 + ((a_c ^ ((a_r >> 1) & 3)) * 8);   // short units

    f32x4 acc[4][4];
#pragma unroll
    for (int i = 0; i < 4; ++i)
#pragma unroll
        for (int j = 0; j < 4; ++j) acc[i][j] = (f32x4){0.f, 0.f, 0.f, 0.f};

    // ---- prologue: stage kt=0 ----
    {
        gload_lds16(w1b + b_off0, (char*)&lds_b[0][0] + b_dst0);
        gload_lds16(w1b + b_off1, (char*)&lds_b[0][0] + b_dst1);
        float4 f0 = *(const float4*)(q + a_goff);
        float4 f1 = *(const float4*)(q + a_goff + 4);
        bf16x8 pk;
        pk[0] = f2bf(f0.x); pk[1] = f2bf(f0.y); pk[2] = f2bf(f0.z); pk[3] = f2bf(f0.w);
        pk[4] = f2bf(f1.x); pk[5] = f2bf(f1.y); pk[6] = f2bf(f1.z); pk[7] = f2bf(f1.w);
        *(bf16x8*)&lds_a[0][a_ldst] = pk;
    }
    __syncthreads();

#pragma unroll
    for (int kt = 0; kt < 16; ++kt) {
        const int cur = kt & 1, nxt = cur ^ 1;

        // prefetch next tile: A -> regs (early issue), B -> LDS (async)
        float4 f0, f1;
        if (kt < 15) {
            const float* abase = (kt + 1 < 8) ? q : kk_;
            const int koff = ((kt + 1) & 7) * 32;
            f0 = *(const float4*)(abase + a_goff + koff);
            f1 = *(const float4*)(abase + a_goff + koff + 4);
            gload_lds16(w1b + b_off0 + (size_t)(kt + 1) * 32, (char*)&lds_b[nxt][0] + b_dst0);
            gload_lds16(w1b + b_off1 + (size_t)(kt + 1) * 32, (char*)&lds_b[nxt][0] + b_dst1);
        }

        // fragments from current buffers
        bf16x8 af[4], bfv[4];
#pragma unroll
        for (int fm = 0; fm < 4; ++fm) {
            const int r = wm * 64 + fm * 16 + l15;
            af[fm] = *(const bf16x8*)&lds_a[cur][r * 32 + ((lhi ^ ((r >> 1) & 3)) * 8)];
        }
#pragma unroll
        for (int fn = 0; fn < 4; ++fn) {
            const int d = wn * 64 + fn * 16 + l15;
            bfv[fn] = *(const bf16x8*)&lds_b[cur][d * 32 + ((lhi ^ ((d >> 1) & 3)) * 8)];
        }
#pragma unroll
        for (int fm = 0; fm < 4; ++fm)
#pragma unroll
            for (int fn = 0; fn < 4; ++fn)
                acc[fm][fn] = __builtin_amdgcn_mfma_f32_16x16x32_bf16(
                    af[fm], bfv[fn], acc[fm][fn], 0, 0, 0);

        // write prefetched A into next buffer
        if (kt < 15) {
            bf16x8 pk;
            pk[0] = f2bf(f0.x); pk[1] = f2bf(f0.y); pk[2] = f2bf(f0.z); pk[3] = f2bf(f0.w);
            pk[4] = f2bf(f1.x); pk[5] = f2bf(f1.y); pk[6] = f2bf(f1.z); pk[7] = f2bf(f1.w);
            *(bf16x8*)&lds_a[nxt][a_ldst] = pk;
        }
        __syncthreads();
    }

    // ---- epilogue: bias + lrelu + dot(w2) + exp + atomicAdd(segsum) ----
    // wave wn owns head wn entirely (cols wn*64..wn*64+63).
    float bias[4], w2v[4];
#pragma unroll
    for (int fn = 0; fn < 4; ++fn) {
        int col = wn * 64 + fn * 16 + l15;
        bias[fn] = b1[col];
        w2v[fn]  = w2[col];
    }
#pragma unroll
    for (int fm = 0; fm < 4; ++fm) {
#pragma unroll
        for (int r = 0; r < 4; ++r) {
            int row = row0 + wm * 64 + fm * 16 + lhi * 4 + r;  // C/D: row=(l>>4)*4+reg
            float p = 0.f;
#pragma unroll
            for (int fn = 0; fn < 4; ++fn) {
                float y = acc[fm][fn][r] + bias[fn];
                y = (y > 0.f) ? y : 0.01f * y;
                p += y * w2v[fn];
            }
#pragma unroll
            for (int m = 1; m < 16; m <<= 1) p += __shfl_xor(p, m);
            if (l15 == 0) {
                float e = __expf(p);
                attn[(size_t)row * 4 + wn] = e;
                atomicAdd(&segsum[index[row] * 4 + wn], e);
            }
        }
    }
}

__global__ void seg_norm(const float* __restrict__ attn, const int* __restrict__ index,
                         const float* __restrict__ segsum, float* __restrict__ out, int total) {
    int i = blockIdx.x * blockDim.x + threadIdx.x;
    if (i >= total) return;
    int e = i >> 2, h = i & 3;
    out[i] = attn[i] / (segsum[index[e] * 4 + h] + 1e-16f);
}

extern "C" void kernel_launch(void* const* d_in, const int* in_sizes, int n_in,
                              void* d_out, int out_size, void* d_ws, size_t ws_size,
                              hipStream_t stream) {
    const float* q   = (const float*)d_in[0];
    const float* k   = (const float*)d_in[1];
    const float* w1  = (const float*)d_in[2];
    const float* b1  = (const float*)d_in[3];
    const float* w2  = (const float*)d_in[4];
    const int* index = (const int*)d_in[5];

    const int nE = in_sizes[0] / 256;      // 320000
    char* ws = (char*)d_ws;
    float* attn   = (float*)ws;            ws += (size_t)nE * 4 * 4;
    float* segsum = (float*)ws;            ws += (size_t)NNODES * 4 * 4;
    short* w1bf   = (short*)ws;            // 256*512 bf16 = 256KB
    float* out    = (float*)d_out;

    w1_cvt<<<128, 256, 0, stream>>>(w1, w1bf);
    seg_init<<<(NNODES * 4 + 255) / 256, 256, 0, stream>>>(segsum, NNODES * 4);

    attn_gemm<<<nE / 128, 512, 0, stream>>>(q, k, w1bf, b1, w2, index, attn, segsum);

    int total = nE * 4;
    seg_norm<<<(total + 255) / 256, 256, 0, stream>>>(attn, index, segsum, out, total);
}